// Round 4
// baseline (2083.825 us; speedup 1.0000x reference)
//
#include <hip/hip_runtime.h>

typedef unsigned int u32;

#define NBATCH 8
#define NH 256
#define NW 256
#define NC 32
#define NHID 256
#define NK 96           // 3*NC perceive features
#define W1T_STRIDE 36   // padded LDS stride for transposed fc1_w (16B aligned, conflict-light)

// ---------------- JAX threefry-2x32 (exact port of jax._src.prng) ----------------
__host__ __device__ inline u32 rotl32(u32 v, u32 d) { return (v << d) | (v >> (32u - d)); }

__host__ __device__ inline void tf2x32(u32 ks0, u32 ks1, u32& x0, u32& x1) {
  const u32 ks2 = ks0 ^ ks1 ^ 0x1BD11BDAu;
  x0 += ks0; x1 += ks1;
#define TFR(r) { x0 += x1; x1 = rotl32(x1, r); x1 ^= x0; }
  TFR(13u) TFR(15u) TFR(26u) TFR(6u)
  x0 += ks1; x1 += ks2 + 1u;
  TFR(17u) TFR(29u) TFR(16u) TFR(24u)
  x0 += ks2; x1 += ks0 + 2u;
  TFR(13u) TFR(15u) TFR(26u) TFR(6u)
  x0 += ks0; x1 += ks1 + 3u;
  TFR(17u) TFR(29u) TFR(16u) TFR(24u)
  x0 += ks1; x1 += ks2 + 4u;
  TFR(13u) TFR(15u) TFR(26u) TFR(6u)
  x0 += ks2; x1 += ks0 + 5u;
#undef TFR
}

// ---------------- one NCA step ----------------
// grid = B*H blocks of NW threads; thread = one pixel (b,h,w)
__global__ __launch_bounds__(256) void nca_step(
    const float* __restrict__ xin, float* __restrict__ xout,
    const float* __restrict__ w0, const float* __restrict__ b0,
    const float* __restrict__ w1, u32 fk0, u32 fk1)
{
  __shared__ float w1t[NHID * W1T_STRIDE];  // w1t[o][c] = fc1_w[c][o]

  const int tid = threadIdx.x;
  // transpose fc1_w [32][256] -> LDS [256][36-padded]
  #pragma unroll
  for (int i = 0; i < NC; ++i) {
    // flat element e = i*256 + tid : c = i, o = tid  (coalesced global read)
    w1t[tid * W1T_STRIDE + i] = w1[i * NHID + tid];
  }
  __syncthreads();

  const int w  = tid;
  const int bh = blockIdx.x;          // b*NH + h
  const int h  = bh & (NH - 1);
  const int b  = bh >> 8;
  const size_t img = (size_t)b * (NH * NW);

  // ---- perceive: y[0:32]=x, y[32:64]=conv(KX) (grad along H), y[64:96]=conv(KY) (grad along W) ----
  float y[NK];
  #pragma unroll
  for (int k = NC; k < NK; ++k) y[k] = 0.0f;

  // center (KX/KY center weights are 0 -> only identity part)
  {
    const float4* px = reinterpret_cast<const float4*>(xin + (img + (size_t)h * NW + w) * NC);
    #pragma unroll
    for (int i = 0; i < NC / 4; ++i) {
      float4 v = px[i];
      y[4*i+0] = v.x; y[4*i+1] = v.y; y[4*i+2] = v.z; y[4*i+3] = v.w;
    }
  }
  // 8 neighbors; KX[di,dj] = di*(dj==0?2:1)/8 ; KY[di,dj] = (di==0?2:1)*dj/8 ; zero pad
  constexpr int ndi[8] = {-1,-1,-1, 0, 0, 1, 1, 1};
  constexpr int ndj[8] = {-1, 0, 1,-1, 1,-1, 0, 1};
  #pragma unroll
  for (int n = 0; n < 8; ++n) {
    const int di = ndi[n], dj = ndj[n];
    const float kx = (float)di * ((dj == 0) ? 2.0f : 1.0f) * 0.125f;
    const float ky = ((di == 0) ? 2.0f : 1.0f) * (float)dj * 0.125f;
    const int hh = h + di, ww = w + dj;
    if (hh >= 0 && hh < NH && ww >= 0 && ww < NW) {
      const float4* px = reinterpret_cast<const float4*>(xin + (img + (size_t)hh * NW + ww) * NC);
      #pragma unroll
      for (int i = 0; i < NC / 4; ++i) {
        float4 v = px[i];
        if (kx != 0.0f) {
          y[NC + 4*i+0] += kx * v.x; y[NC + 4*i+1] += kx * v.y;
          y[NC + 4*i+2] += kx * v.z; y[NC + 4*i+3] += kx * v.w;
        }
        if (ky != 0.0f) {
          y[2*NC + 4*i+0] += ky * v.x; y[2*NC + 4*i+1] += ky * v.y;
          y[2*NC + 4*i+2] += ky * v.z; y[2*NC + 4*i+3] += ky * v.w;
        }
      }
    }
  }

  // ---- MLP: h_o = b0[o] + y . w0[o,:] ; d_c += h_o * w1t[o][c] ----
  float d[NC];
  #pragma unroll
  for (int c = 0; c < NC; ++c) d[c] = 0.0f;

  #pragma unroll 2
  for (int o = 0; o < NHID; ++o) {
    // 4-way split accumulator: breaks the serial FMA chain (reassoc ok, thr=2e-2)
    float h0 = b0[o], h1 = 0.0f, h2 = 0.0f, h3 = 0.0f;
    const float* wr0 = w0 + (size_t)o * NK;   // uniform address -> s_load broadcast
    #pragma unroll
    for (int k = 0; k < NK; k += 4) {
      h0 += y[k+0] * wr0[k+0];
      h1 += y[k+1] * wr0[k+1];
      h2 += y[k+2] * wr0[k+2];
      h3 += y[k+3] * wr0[k+3];
    }
    const float hacc = (h0 + h1) + (h2 + h3);
    const float* wr1 = &w1t[o * W1T_STRIDE]; // LDS broadcast, 16B aligned
    #pragma unroll
    for (int c = 0; c < NC; ++c) d[c] += hacc * wr1[c];
  }

  // ---- fire mask: JAX threefry, PARTITIONABLE scheme (jax_threefry_partitionable=True,
  //      default in modern JAX). Element at flat index p uses the 64-bit counter p
  //      expressed as two 32-bit words (hi,lo)=(0,p) via iota_2x32_shape; for 32-bit
  //      output, bits = out0 ^ out1. (Legacy split-iota scheme gave absmax 0.168.)
  const u32 p  = (u32)bh * NW + (u32)w;
  u32 a0 = 0u, a1 = p;
  tf2x32(fk0, fk1, a0, a1);
  const u32 bits = a0 ^ a1;
  const float u  = __uint_as_float((bits >> 9) | 0x3F800000u) - 1.0f;
  const float m  = (u > 0.5f) ? 1.0f : 0.0f;

  // ---- x2 = sigmoid(x + d*mask); keep channels 0..2 from x ----
  float ov[NC];
  #pragma unroll
  for (int c = 0; c < NC; ++c) {
    const float xi = y[c];
    const float t  = xi + d[c] * m;
    const float s  = 1.0f / (1.0f + __expf(-t));
    ov[c] = (c < 3) ? xi : s;
  }
  float4* po = reinterpret_cast<float4*>(xout + (img + (size_t)h * NW + w) * NC);
  #pragma unroll
  for (int i = 0; i < NC / 4; ++i)
    po[i] = make_float4(ov[4*i+0], ov[4*i+1], ov[4*i+2], ov[4*i+3]);
}

// ---------------- host ----------------
static void fold_key(u32 step, u32& fk0, u32& fk1) {
  // jax.random.fold_in(jax.random.key(42), step) == threefry((0,42),(0,step))
  // (fold_in is a direct 2-element threefry call; unaffected by partitionable flag)
  u32 x0 = 0u, x1 = step;
  tf2x32(0u, 42u, x0, x1);
  fk0 = x0; fk1 = x1;
}

extern "C" void kernel_launch(void* const* d_in, const int* in_sizes, int n_in,
                              void* d_out, int out_size, void* d_ws, size_t ws_size,
                              hipStream_t stream) {
  const float* x  = (const float*)d_in[0];
  const float* w0 = (const float*)d_in[1];
  const float* b0 = (const float*)d_in[2];
  const float* w1 = (const float*)d_in[3];
  // steps is fixed at 2 by setup_inputs()
  float* xmid = (float*)d_ws;     // 67 MB intermediate (step-1 output)
  float* xout = (float*)d_out;

  u32 fka0, fka1, fkb0, fkb1;
  fold_key(0u, fka0, fka1);
  fold_key(1u, fkb0, fkb1);

  dim3 grid(NBATCH * NH), blk(NW);
  nca_step<<<grid, blk, 0, stream>>>(x,    xmid, w0, b0, w1, fka0, fka1);
  nca_step<<<grid, blk, 0, stream>>>(xmid, xout, w0, b0, w1, fkb0, fkb1);
}

// Round 5
// 727.934 us; speedup vs baseline: 2.8627x; 2.8627x over previous
//
#include <hip/hip_runtime.h>
#include <hip/hip_bf16.h>

typedef unsigned int u32;
typedef __attribute__((ext_vector_type(8))) short bf16x8;   // 8 bf16 = 4 VGPRs (MFMA A/B frag)
typedef __attribute__((ext_vector_type(4))) short s16x4;    // 4 bf16 = 8B
typedef __attribute__((ext_vector_type(4))) float f32x4;    // MFMA C/D frag

#define NB 8
#define NH 256
#define NW 256
#define NC 32
#define NHID 256
#define NK 96
#define YS 104    // Y LDS row stride (bf16 elems): 96 + 8 pad, 16B-aligned rows, anti-conflict
#define HS 264    // H LDS row stride (bf16 elems): 256 + 8 pad
#define XCS 36    // xc LDS row stride (f32)

// ---------------- JAX threefry-2x32 ----------------
__host__ __device__ inline u32 rotl32(u32 v, u32 d) { return (v << d) | (v >> (32u - d)); }

__host__ __device__ inline void tf2x32(u32 ks0, u32 ks1, u32& x0, u32& x1) {
  const u32 ks2 = ks0 ^ ks1 ^ 0x1BD11BDAu;
  x0 += ks0; x1 += ks1;
#define TFR(r) { x0 += x1; x1 = rotl32(x1, r); x1 ^= x0; }
  TFR(13u) TFR(15u) TFR(26u) TFR(6u)
  x0 += ks1; x1 += ks2 + 1u;
  TFR(17u) TFR(29u) TFR(16u) TFR(24u)
  x0 += ks2; x1 += ks0 + 2u;
  TFR(13u) TFR(15u) TFR(26u) TFR(6u)
  x0 += ks0; x1 += ks1 + 3u;
  TFR(17u) TFR(29u) TFR(16u) TFR(24u)
  x0 += ks1; x1 += ks2 + 4u;
  TFR(13u) TFR(15u) TFR(26u) TFR(6u)
  x0 += ks2; x1 += ks0 + 5u;
#undef TFR
}

__device__ inline short bfr(float f) {
  __hip_bfloat16 h = __float2bfloat16(f);   // RNE; compiler fuses pairs into v_cvt_pk_bf16_f32
  return __builtin_bit_cast(short, h);
}

// ---------------- fused NCA step (MFMA) ----------------
// grid = B * H * (W/32); block = 256 threads (4 waves); 32 pixels per block.
// GEMM1: H^T[256 hid][32 pix] = W0 * Y^T + b0  (K=96), 16x16x32 bf16 MFMA
// GEMM2: D^T[32 c][32 pix]    = W1 * H^T       (K=256)
// Note: A and B fragments are loaded with the SAME per-lane k-rule (8 contiguous
// k at offset 8*(lane>>4)); since CDNA A/B lane layouts mirror each other, the
// dot product is invariant to the true hardware k-permutation. Only the C/D
// mapping (col=lane&15, row=4*(lane>>4)+reg — HW-verified) is load-bearing.
__global__ __launch_bounds__(256) void nca_step_mfma(
    const float* __restrict__ xin, float* __restrict__ xout,
    const float* __restrict__ w0, const float* __restrict__ b0,
    const float* __restrict__ w1, u32 fk0, u32 fk1)
{
  __shared__ __align__(16) short Ys[32 * YS];   // Y[pix][feat] bf16
  __shared__ __align__(16) short Hs[32 * HS];   // H[pix][hid]  bf16
  __shared__ __align__(16) float XC[32 * XCS];  // center x fp32 (exact pass-through)

  const int tid = threadIdx.x;
  const int bx  = blockIdx.x;
  const int wt  = bx & 7;               // w-tile within row
  const int h   = (bx >> 3) & (NH - 1);
  const int b   = bx >> 11;
  const int wbase = wt * 32;
  const size_t rowpix = ((size_t)b * NH + h) * NW;   // flat pixel idx of (b,h,0)

  // ---------- Phase A: perceive -> Ys (bf16) + XC (fp32) ----------
  {
    const int pix = tid >> 3;          // 0..31
    const int cq  = tid & 7;           // channel quad: channels cq*4 .. cq*4+3
    const int w   = wbase + pix;
    float idv[4] = {0.f, 0.f, 0.f, 0.f};
    float gx[4]  = {0.f, 0.f, 0.f, 0.f};
    float gy[4]  = {0.f, 0.f, 0.f, 0.f};
    #pragma unroll
    for (int di = -1; di <= 1; ++di) {
      #pragma unroll
      for (int dj = -1; dj <= 1; ++dj) {
        const int hh = h + di, ww = w + dj;
        if (hh < 0 || hh >= NH || ww < 0 || ww >= NW) continue;   // zero pad
        const float4 v = *reinterpret_cast<const float4*>(
            xin + (((size_t)b * NH + hh) * NW + ww) * NC + cq * 4);
        const float kx = (float)di * ((dj == 0) ? 2.f : 1.f) * 0.125f;
        const float ky = ((di == 0) ? 2.f : 1.f) * (float)dj * 0.125f;
        const float vv[4] = {v.x, v.y, v.z, v.w};
        #pragma unroll
        for (int i = 0; i < 4; ++i) {
          if (di == 0 && dj == 0) idv[i] = vv[i];
          gx[i] += kx * vv[i];
          gy[i] += ky * vv[i];
        }
      }
    }
    s16x4 sid, sgx, sgy;
    #pragma unroll
    for (int i = 0; i < 4; ++i) { sid[i] = bfr(idv[i]); sgx[i] = bfr(gx[i]); sgy[i] = bfr(gy[i]); }
    *reinterpret_cast<s16x4*>(&Ys[pix * YS +          cq * 4]) = sid;
    *reinterpret_cast<s16x4*>(&Ys[pix * YS + NC     + cq * 4]) = sgx;
    *reinterpret_cast<s16x4*>(&Ys[pix * YS + 2 * NC + cq * 4]) = sgy;
    *reinterpret_cast<float4*>(&XC[pix * XCS + cq * 4]) = make_float4(idv[0], idv[1], idv[2], idv[3]);
  }
  __syncthreads();

  const int wid = tid >> 6;   // wave 0..3
  const int l   = tid & 63;
  const int l15 = l & 15;
  const int g   = l >> 4;

  // ---------- Phase B: GEMM1  H^T = W0 * Y^T + b0 ----------
  // B-frags from Ys (shared across this wave's 4 hid-tiles): [pt][kk]
  bf16x8 yb[2][3];
  #pragma unroll
  for (int pt = 0; pt < 2; ++pt)
    #pragma unroll
    for (int kk = 0; kk < 3; ++kk)
      yb[pt][kk] = *reinterpret_cast<const bf16x8*>(&Ys[(pt * 16 + l15) * YS + kk * 32 + g * 8]);

  f32x4 acc[4][2];
  #pragma unroll
  for (int hti = 0; hti < 4; ++hti) {
    const int ht = wid * 4 + hti;
    const float4 bb = *reinterpret_cast<const float4*>(b0 + ht * 16 + 4 * g);  // hid = ht*16+4g+r
    acc[hti][0] = f32x4{bb.x, bb.y, bb.z, bb.w};
    acc[hti][1] = acc[hti][0];
  }
  #pragma unroll
  for (int hti = 0; hti < 4; ++hti) {
    const int ht = wid * 4 + hti;
    const float* arow = w0 + (size_t)(ht * 16 + l15) * NK;   // A row = fc0_w[hid][:]
    #pragma unroll
    for (int kk = 0; kk < 3; ++kk) {
      const float4 a0 = *reinterpret_cast<const float4*>(arow + kk * 32 + g * 8);
      const float4 a1 = *reinterpret_cast<const float4*>(arow + kk * 32 + g * 8 + 4);
      bf16x8 af;
      af[0] = bfr(a0.x); af[1] = bfr(a0.y); af[2] = bfr(a0.z); af[3] = bfr(a0.w);
      af[4] = bfr(a1.x); af[5] = bfr(a1.y); af[6] = bfr(a1.z); af[7] = bfr(a1.w);
      acc[hti][0] = __builtin_amdgcn_mfma_f32_16x16x32_bf16(af, yb[0][kk], acc[hti][0], 0, 0, 0);
      acc[hti][1] = __builtin_amdgcn_mfma_f32_16x16x32_bf16(af, yb[1][kk], acc[hti][1], 0, 0, 0);
    }
  }
  // store H^T tiles to Hs[pix][hid] (bf16): lane holds hid = ht*16+4g+r, pix = pt*16+l15
  #pragma unroll
  for (int hti = 0; hti < 4; ++hti) {
    const int ht = wid * 4 + hti;
    #pragma unroll
    for (int pt = 0; pt < 2; ++pt) {
      s16x4 hv;
      #pragma unroll
      for (int r = 0; r < 4; ++r) hv[r] = bfr(acc[hti][pt][r]);
      *reinterpret_cast<s16x4*>(&Hs[(pt * 16 + l15) * HS + ht * 16 + 4 * g]) = hv;
    }
  }
  __syncthreads();

  // ---------- Phase C: GEMM2  D^T = W1 * H^T ----------
  const int ct = wid & 1;     // c-tile (0..1)
  const int pt = wid >> 1;    // pix-tile (0..1)
  f32x4 dacc = {0.f, 0.f, 0.f, 0.f};
  const float* a1row = w1 + (size_t)(ct * 16 + l15) * NHID;  // A row = fc1_w[c][:]
  #pragma unroll
  for (int kk = 0; kk < 8; ++kk) {
    const float4 a0 = *reinterpret_cast<const float4*>(a1row + kk * 32 + g * 8);
    const float4 a1v = *reinterpret_cast<const float4*>(a1row + kk * 32 + g * 8 + 4);
    bf16x8 af;
    af[0] = bfr(a0.x); af[1] = bfr(a0.y); af[2] = bfr(a0.z); af[3] = bfr(a0.w);
    af[4] = bfr(a1v.x); af[5] = bfr(a1v.y); af[6] = bfr(a1v.z); af[7] = bfr(a1v.w);
    const bf16x8 hf = *reinterpret_cast<const bf16x8*>(&Hs[(pt * 16 + l15) * HS + kk * 32 + g * 8]);
    dacc = __builtin_amdgcn_mfma_f32_16x16x32_bf16(af, hf, dacc, 0, 0, 0);
  }

  // ---------- Phase D: mask + sigmoid + write ----------
  const int pix = pt * 16 + l15;                    // block-local pixel
  const u32 p = (u32)(rowpix + wbase + pix);        // flat pixel index
  u32 r0 = 0u, r1 = p;
  tf2x32(fk0, fk1, r0, r1);
  const u32 bits = r0 ^ r1;                         // partitionable scheme, verified R4
  const float uu = __uint_as_float((bits >> 9) | 0x3F800000u) - 1.0f;
  const float m  = (uu > 0.5f) ? 1.f : 0.f;

  const float4 xcv = *reinterpret_cast<const float4*>(&XC[pix * XCS + ct * 16 + 4 * g]);
  const float xc4[4] = {xcv.x, xcv.y, xcv.z, xcv.w};
  float ov[4];
  #pragma unroll
  for (int r = 0; r < 4; ++r) {
    const int c = ct * 16 + 4 * g + r;
    const float t = xc4[r] + dacc[r] * m;
    const float s = 1.f / (1.f + __expf(-t));
    ov[r] = (c < 3) ? xc4[r] : s;
  }
  *reinterpret_cast<float4*>(xout + (rowpix + wbase + pix) * NC + ct * 16 + 4 * g) =
      make_float4(ov[0], ov[1], ov[2], ov[3]);
}

// ---------------- host ----------------
static void fold_key(u32 step, u32& fk0, u32& fk1) {
  u32 x0 = 0u, x1 = step;
  tf2x32(0u, 42u, x0, x1);
  fk0 = x0; fk1 = x1;
}

extern "C" void kernel_launch(void* const* d_in, const int* in_sizes, int n_in,
                              void* d_out, int out_size, void* d_ws, size_t ws_size,
                              hipStream_t stream) {
  const float* x  = (const float*)d_in[0];
  const float* w0 = (const float*)d_in[1];
  const float* b0 = (const float*)d_in[2];
  const float* w1 = (const float*)d_in[3];
  float* xmid = (float*)d_ws;     // 67 MB step-1 intermediate
  float* xout = (float*)d_out;

  u32 fka0, fka1, fkb0, fkb1;
  fold_key(0u, fka0, fka1);
  fold_key(1u, fkb0, fkb1);

  dim3 grid(NB * NH * (NW / 32)), blk(256);
  nca_step_mfma<<<grid, blk, 0, stream>>>(x,    xmid, w0, b0, w1, fka0, fka1);
  nca_step_mfma<<<grid, blk, 0, stream>>>(xmid, xout, w0, b0, w1, fkb0, fkb1);
}

// Round 6
// 480.834 us; speedup vs baseline: 4.3338x; 1.5139x over previous
//
#include <hip/hip_runtime.h>
#include <hip/hip_bf16.h>

typedef unsigned int u32;
typedef __attribute__((ext_vector_type(8))) short bf16x8;   // MFMA A/B frag (4 VGPRs)
typedef __attribute__((ext_vector_type(4))) short s16x4;    // 4 bf16 = 8B
typedef __attribute__((ext_vector_type(4))) float f32x4;    // MFMA C/D frag

#define NB 8
#define NH 256
#define NW 256
#define NC 32
#define NHID 256
#define NK 96
#define YS 104    // Y LDS row stride (bf16): 96+8 pad
#define HS 264    // H LDS row stride (bf16): 256+8 pad
#define XCS 36    // center-x LDS row stride (f32)
#define NTILES 4  // 4 x 32-pixel tiles per block = 128 pixels

// ---------------- JAX threefry-2x32 ----------------
__host__ __device__ inline u32 rotl32(u32 v, u32 d) { return (v << d) | (v >> (32u - d)); }

__host__ __device__ inline void tf2x32(u32 ks0, u32 ks1, u32& x0, u32& x1) {
  const u32 ks2 = ks0 ^ ks1 ^ 0x1BD11BDAu;
  x0 += ks0; x1 += ks1;
#define TFR(r) { x0 += x1; x1 = rotl32(x1, r); x1 ^= x0; }
  TFR(13u) TFR(15u) TFR(26u) TFR(6u)
  x0 += ks1; x1 += ks2 + 1u;
  TFR(17u) TFR(29u) TFR(16u) TFR(24u)
  x0 += ks2; x1 += ks0 + 2u;
  TFR(13u) TFR(15u) TFR(26u) TFR(6u)
  x0 += ks0; x1 += ks1 + 3u;
  TFR(17u) TFR(29u) TFR(16u) TFR(24u)
  x0 += ks1; x1 += ks2 + 4u;
  TFR(13u) TFR(15u) TFR(26u) TFR(6u)
  x0 += ks2; x1 += ks0 + 5u;
#undef TFR
}

__device__ inline short bfr(float f) {
  __hip_bfloat16 h = __float2bfloat16(f);   // RNE
  return __builtin_bit_cast(short, h);
}

// ---------------- fused NCA step (MFMA, 128 pix/block) ----------------
// grid = B*H*(W/128) = 4096 blocks of 256 threads (4 waves).
// Weight fragments hoisted to registers ONCE per block; 4 pixel-tiles looped.
// GEMM1: H^T[256][32] = W0 * Y^T + b0 (K=96); hid split across 4 waves.
// GEMM2: D^T[32][32]  = W1 * H^T (K=256); (c-half, pix-half) per wave.
// A and B frags use the same per-lane k-rule (k-permutation-invariant);
// C/D mapping col=lane&15, row=4*(lane>>4)+reg is the HW-verified one.
__global__ __launch_bounds__(256) void nca_step_mfma(
    const float* __restrict__ xin, float* __restrict__ xout,
    const float* __restrict__ w0, const float* __restrict__ b0,
    const float* __restrict__ w1, u32 fk0, u32 fk1)
{
  __shared__ __align__(16) short Ys[32 * YS];
  __shared__ __align__(16) short Hs[32 * HS];
  __shared__ __align__(16) float XC[32 * XCS];

  const int tid = threadIdx.x;
  const int bx  = blockIdx.x;
  const int wt  = bx & 1;                  // which 128-pixel half of the row
  const int h   = (bx >> 1) & (NH - 1);
  const int b   = bx >> 9;
  const int wbase0 = wt * 128;
  const size_t rowpix = ((size_t)b * NH + h) * NW;

  const int wid = tid >> 6;
  const int l   = tid & 63;
  const int l15 = l & 15;
  const int g   = l >> 4;

  // ---- hoist weights to registers (bf16), once per block ----
  bf16x8 af1[4][3];                        // GEMM1 A: hid-tiles wid*4+hti, k-chunks kk
  #pragma unroll
  for (int hti = 0; hti < 4; ++hti) {
    const float* arow = w0 + (size_t)((wid * 4 + hti) * 16 + l15) * NK;
    #pragma unroll
    for (int kk = 0; kk < 3; ++kk) {
      const float4 a0 = *reinterpret_cast<const float4*>(arow + kk * 32 + g * 8);
      const float4 a1 = *reinterpret_cast<const float4*>(arow + kk * 32 + g * 8 + 4);
      bf16x8 af;
      af[0] = bfr(a0.x); af[1] = bfr(a0.y); af[2] = bfr(a0.z); af[3] = bfr(a0.w);
      af[4] = bfr(a1.x); af[5] = bfr(a1.y); af[6] = bfr(a1.z); af[7] = bfr(a1.w);
      af1[hti][kk] = af;
    }
  }
  const int ct = wid & 1;                  // GEMM2 c-tile
  const int pt = wid >> 1;                 // GEMM2 pix-tile
  bf16x8 af2[8];
  {
    const float* a1row = w1 + (size_t)(ct * 16 + l15) * NHID;
    #pragma unroll
    for (int kk = 0; kk < 8; ++kk) {
      const float4 a0 = *reinterpret_cast<const float4*>(a1row + kk * 32 + g * 8);
      const float4 a1v = *reinterpret_cast<const float4*>(a1row + kk * 32 + g * 8 + 4);
      bf16x8 af;
      af[0] = bfr(a0.x); af[1] = bfr(a0.y); af[2] = bfr(a0.z); af[3] = bfr(a0.w);
      af[4] = bfr(a1v.x); af[5] = bfr(a1v.y); af[6] = bfr(a1v.z); af[7] = bfr(a1v.w);
      af2[kk] = af;
    }
  }
  f32x4 bb[4];                             // bias frags: hid = (wid*4+hti)*16 + 4g + r
  #pragma unroll
  for (int hti = 0; hti < 4; ++hti) {
    const float4 t4 = *reinterpret_cast<const float4*>(b0 + (wid * 4 + hti) * 16 + 4 * g);
    bb[hti] = f32x4{t4.x, t4.y, t4.z, t4.w};
  }

  const int apix = tid >> 3;               // phase-A pixel 0..31
  const int cq   = tid & 7;                // phase-A channel quad

  for (int t = 0; t < NTILES; ++t) {
    const int wbase = wbase0 + t * 32;
    __syncthreads();   // WAR: previous tile's readers of Ys/XC/Hs are done

    // ---------- Phase A: perceive -> Ys (bf16) + XC (fp32) ----------
    {
      const int w = wbase + apix;
      float idv[4] = {0.f,0.f,0.f,0.f}, gx[4] = {0.f,0.f,0.f,0.f}, gy[4] = {0.f,0.f,0.f,0.f};
      #pragma unroll
      for (int di = -1; di <= 1; ++di) {
        #pragma unroll
        for (int dj = -1; dj <= 1; ++dj) {
          const int hh = h + di, ww = w + dj;
          if (hh < 0 || hh >= NH || ww < 0 || ww >= NW) continue;  // zero pad
          const float4 v = *reinterpret_cast<const float4*>(
              xin + (((size_t)b * NH + hh) * NW + ww) * NC + cq * 4);
          const float kx = (float)di * ((dj == 0) ? 2.f : 1.f) * 0.125f;
          const float ky = ((di == 0) ? 2.f : 1.f) * (float)dj * 0.125f;
          const float vv[4] = {v.x, v.y, v.z, v.w};
          #pragma unroll
          for (int i = 0; i < 4; ++i) {
            if (di == 0 && dj == 0) idv[i] = vv[i];
            gx[i] += kx * vv[i];
            gy[i] += ky * vv[i];
          }
        }
      }
      s16x4 sid, sgx, sgy;
      #pragma unroll
      for (int i = 0; i < 4; ++i) { sid[i] = bfr(idv[i]); sgx[i] = bfr(gx[i]); sgy[i] = bfr(gy[i]); }
      *reinterpret_cast<s16x4*>(&Ys[apix * YS +          cq * 4]) = sid;
      *reinterpret_cast<s16x4*>(&Ys[apix * YS + NC     + cq * 4]) = sgx;
      *reinterpret_cast<s16x4*>(&Ys[apix * YS + 2 * NC + cq * 4]) = sgy;
      *reinterpret_cast<float4*>(&XC[apix * XCS + cq * 4]) =
          make_float4(idv[0], idv[1], idv[2], idv[3]);
    }
    __syncthreads();

    // ---------- GEMM1: H^T = W0 * Y^T + b0 (A in registers) ----------
    bf16x8 yb[2][3];
    #pragma unroll
    for (int p2 = 0; p2 < 2; ++p2)
      #pragma unroll
      for (int kk = 0; kk < 3; ++kk)
        yb[p2][kk] = *reinterpret_cast<const bf16x8*>(&Ys[(p2 * 16 + l15) * YS + kk * 32 + g * 8]);

    f32x4 acc[4][2];
    #pragma unroll
    for (int hti = 0; hti < 4; ++hti) { acc[hti][0] = bb[hti]; acc[hti][1] = bb[hti]; }
    #pragma unroll
    for (int hti = 0; hti < 4; ++hti)
      #pragma unroll
      for (int kk = 0; kk < 3; ++kk) {
        acc[hti][0] = __builtin_amdgcn_mfma_f32_16x16x32_bf16(af1[hti][kk], yb[0][kk], acc[hti][0], 0, 0, 0);
        acc[hti][1] = __builtin_amdgcn_mfma_f32_16x16x32_bf16(af1[hti][kk], yb[1][kk], acc[hti][1], 0, 0, 0);
      }
    #pragma unroll
    for (int hti = 0; hti < 4; ++hti) {
      const int ht = wid * 4 + hti;
      #pragma unroll
      for (int p2 = 0; p2 < 2; ++p2) {
        s16x4 hv;
        #pragma unroll
        for (int r = 0; r < 4; ++r) hv[r] = bfr(acc[hti][p2][r]);
        *reinterpret_cast<s16x4*>(&Hs[(p2 * 16 + l15) * HS + ht * 16 + 4 * g]) = hv;
      }
    }
    __syncthreads();

    // ---------- GEMM2: D^T = W1 * H^T (A in registers) + epilogue ----------
    f32x4 dacc = {0.f, 0.f, 0.f, 0.f};
    #pragma unroll
    for (int kk = 0; kk < 8; ++kk) {
      const bf16x8 hf = *reinterpret_cast<const bf16x8*>(&Hs[(pt * 16 + l15) * HS + kk * 32 + g * 8]);
      dacc = __builtin_amdgcn_mfma_f32_16x16x32_bf16(af2[kk], hf, dacc, 0, 0, 0);
    }

    const int pix = pt * 16 + l15;
    const u32 p = (u32)(rowpix + wbase + pix);
    u32 r0 = 0u, r1 = p;
    tf2x32(fk0, fk1, r0, r1);
    const u32 bits = r0 ^ r1;              // partitionable threefry (verified R4)
    const float uu = __uint_as_float((bits >> 9) | 0x3F800000u) - 1.0f;
    const float m  = (uu > 0.5f) ? 1.f : 0.f;

    const float4 xcv = *reinterpret_cast<const float4*>(&XC[pix * XCS + ct * 16 + 4 * g]);
    const float xc4[4] = {xcv.x, xcv.y, xcv.z, xcv.w};
    float ov[4];
    #pragma unroll
    for (int r = 0; r < 4; ++r) {
      const int c = ct * 16 + 4 * g + r;
      const float tt = xc4[r] + dacc[r] * m;
      const float s = 1.f / (1.f + __expf(-tt));
      ov[r] = (c < 3) ? xc4[r] : s;
    }
    *reinterpret_cast<float4*>(xout + (rowpix + wbase + pix) * NC + ct * 16 + 4 * g) =
        make_float4(ov[0], ov[1], ov[2], ov[3]);
  }
}

// ---------------- host ----------------
static void fold_key(u32 step, u32& fk0, u32& fk1) {
  u32 x0 = 0u, x1 = step;
  tf2x32(0u, 42u, x0, x1);
  fk0 = x0; fk1 = x1;
}

extern "C" void kernel_launch(void* const* d_in, const int* in_sizes, int n_in,
                              void* d_out, int out_size, void* d_ws, size_t ws_size,
                              hipStream_t stream) {
  const float* x  = (const float*)d_in[0];
  const float* w0 = (const float*)d_in[1];
  const float* b0 = (const float*)d_in[2];
  const float* w1 = (const float*)d_in[3];
  float* xmid = (float*)d_ws;     // 67 MB step-1 intermediate
  float* xout = (float*)d_out;

  u32 fka0, fka1, fkb0, fkb1;
  fold_key(0u, fka0, fka1);
  fold_key(1u, fkb0, fkb1);

  dim3 grid(NB * NH * (NW / 128)), blk(256);
  nca_step_mfma<<<grid, blk, 0, stream>>>(x,    xmid, w0, b0, w1, fka0, fka1);
  nca_step_mfma<<<grid, blk, 0, stream>>>(xmid, xout, w0, b0, w1, fkb0, fkb1);
}

// Round 9
// 345.701 us; speedup vs baseline: 6.0278x; 1.3909x over previous
//
#include <hip/hip_runtime.h>
#include <hip/hip_bf16.h>

typedef unsigned int u32;
typedef __attribute__((ext_vector_type(8))) short bf16x8;   // MFMA A/B frag (4 VGPRs)
typedef __attribute__((ext_vector_type(4))) short s16x4;    // 4 bf16 = 8B
typedef __attribute__((ext_vector_type(4))) float f32x4;    // MFMA C/D frag

#define NB 8
#define NH 256
#define NW 256
#define NC 32
#define NHID 256
#define NK 96
#define YS 104    // Y LDS row stride (bf16): 96+8 pad
#define HS 264    // H LDS row stride (bf16): 256+8 pad
#define XCS 36    // center-x LDS row stride (f32)
#define NTILES 4  // 4 x 32-pixel tiles per block = 128 pixels

// ---------------- JAX threefry-2x32 ----------------
__host__ __device__ inline u32 rotl32(u32 v, u32 d) { return (v << d) | (v >> (32u - d)); }

__host__ __device__ inline void tf2x32(u32 ks0, u32 ks1, u32& x0, u32& x1) {
  const u32 ks2 = ks0 ^ ks1 ^ 0x1BD11BDAu;
  x0 += ks0; x1 += ks1;
#define TFR(r) { x0 += x1; x1 = rotl32(x1, r); x1 ^= x0; }
  TFR(13u) TFR(15u) TFR(26u) TFR(6u)
  x0 += ks1; x1 += ks2 + 1u;
  TFR(17u) TFR(29u) TFR(16u) TFR(24u)
  x0 += ks2; x1 += ks0 + 2u;
  TFR(13u) TFR(15u) TFR(26u) TFR(6u)
  x0 += ks0; x1 += ks1 + 3u;
  TFR(17u) TFR(29u) TFR(16u) TFR(24u)
  x0 += ks1; x1 += ks2 + 4u;
  TFR(13u) TFR(15u) TFR(26u) TFR(6u)
  x0 += ks2; x1 += ks0 + 5u;
#undef TFR
}

__device__ inline short bfr(float f) {
  __hip_bfloat16 h = __float2bfloat16(f);   // RNE
  return __builtin_bit_cast(short, h);
}

// Issue the 9 neighborhood loads for pixel (b,h,w), channel-quad cq.
// Clamped addresses + validity flag: all 9 loads always issue (no divergence);
// out-of-range contributions are zeroed at reduce time.
__device__ inline void issue_loads(const float* __restrict__ xin, int b, int h, int w,
                                   int cq, float4 pf[9], bool vld[9]) {
  #pragma unroll
  for (int n = 0; n < 9; ++n) {
    const int di = n / 3 - 1, dj = n % 3 - 1;
    const int hh = h + di, ww = w + dj;
    vld[n] = (hh >= 0) & (hh < NH) & (ww >= 0) & (ww < NW);
    const int hc = min(max(hh, 0), NH - 1);
    const int wc = min(max(ww, 0), NW - 1);
    pf[n] = *reinterpret_cast<const float4*>(
        xin + (((size_t)b * NH + hc) * NW + wc) * NC + cq * 4);
  }
}

// ---------------- fused NCA step (MFMA, 128 pix/block, pipelined loads) ----------------
// grid = B*H*(W/128) = 4096 blocks of 256 threads (4 waves).
// Weight frags in registers once per block; tile t+1's global loads issued
// during tile t's GEMMs (T14 issue-early/consume-late).
__global__ __launch_bounds__(256) void nca_step_mfma(
    const float* __restrict__ xin, float* __restrict__ xout,
    const float* __restrict__ w0, const float* __restrict__ b0,
    const float* __restrict__ w1, u32 fk0, u32 fk1)
{
  __shared__ __align__(16) short Ys[32 * YS];
  __shared__ __align__(16) short Hs[32 * HS];
  __shared__ __align__(16) float XC[32 * XCS];

  const int tid = threadIdx.x;
  const int bx  = blockIdx.x;
  const int wt  = bx & 1;
  const int h   = (bx >> 1) & (NH - 1);
  const int b   = bx >> 9;
  const int wbase0 = wt * 128;
  const size_t rowpix = ((size_t)b * NH + h) * NW;

  const int wid = tid >> 6;
  const int l   = tid & 63;
  const int l15 = l & 15;
  const int g   = l >> 4;
  const int apix = tid >> 3;               // phase-A pixel 0..31
  const int cq   = tid & 7;                // phase-A channel quad

  // ---- issue tile-0 pixel loads FIRST (fly under the weight hoist) ----
  float4 pf[9]; bool vld[9];
  issue_loads(xin, b, h, wbase0 + apix, cq, pf, vld);

  // ---- hoist weights to registers (bf16), once per block ----
  bf16x8 af1[4][3];
  #pragma unroll
  for (int hti = 0; hti < 4; ++hti) {
    const float* arow = w0 + (size_t)((wid * 4 + hti) * 16 + l15) * NK;
    #pragma unroll
    for (int kk = 0; kk < 3; ++kk) {
      const float4 a0 = *reinterpret_cast<const float4*>(arow + kk * 32 + g * 8);
      const float4 a1 = *reinterpret_cast<const float4*>(arow + kk * 32 + g * 8 + 4);
      bf16x8 af;
      af[0] = bfr(a0.x); af[1] = bfr(a0.y); af[2] = bfr(a0.z); af[3] = bfr(a0.w);
      af[4] = bfr(a1.x); af[5] = bfr(a1.y); af[6] = bfr(a1.z); af[7] = bfr(a1.w);
      af1[hti][kk] = af;
    }
  }
  const int ct = wid & 1;
  const int pt = wid >> 1;
  bf16x8 af2[8];
  {
    const float* a1row = w1 + (size_t)(ct * 16 + l15) * NHID;
    #pragma unroll
    for (int kk = 0; kk < 8; ++kk) {
      const float4 a0 = *reinterpret_cast<const float4*>(a1row + kk * 32 + g * 8);
      const float4 a1v = *reinterpret_cast<const float4*>(a1row + kk * 32 + g * 8 + 4);
      bf16x8 af;
      af[0] = bfr(a0.x); af[1] = bfr(a0.y); af[2] = bfr(a0.z); af[3] = bfr(a0.w);
      af[4] = bfr(a1v.x); af[5] = bfr(a1v.y); af[6] = bfr(a1v.z); af[7] = bfr(a1v.w);
      af2[kk] = af;
    }
  }
  f32x4 bb[4];
  #pragma unroll
  for (int hti = 0; hti < 4; ++hti) {
    const float4 t4 = *reinterpret_cast<const float4*>(b0 + (wid * 4 + hti) * 16 + 4 * g);
    bb[hti] = f32x4{t4.x, t4.y, t4.z, t4.w};
  }

  #pragma unroll 1
  for (int t = 0; t < NTILES; ++t) {
    const int wbase = wbase0 + t * 32;

    // ---------- Phase A: reduce prefetched regs -> Ys (bf16) + XC (fp32) ----------
    {
      float idv[4] = {0.f,0.f,0.f,0.f}, gx[4] = {0.f,0.f,0.f,0.f}, gy[4] = {0.f,0.f,0.f,0.f};
      #pragma unroll
      for (int n = 0; n < 9; ++n) {
        const int di = n / 3 - 1, dj = n % 3 - 1;
        const float kx = (float)di * ((dj == 0) ? 2.f : 1.f) * 0.125f;
        const float ky = ((di == 0) ? 2.f : 1.f) * (float)dj * 0.125f;
        const float vv[4] = {pf[n].x, pf[n].y, pf[n].z, pf[n].w};
        #pragma unroll
        for (int i = 0; i < 4; ++i) {
          const float vm = vld[n] ? vv[i] : 0.f;
          if (di == 0 && dj == 0) idv[i] = vm;
          gx[i] += kx * vm;   // kx==0 terms fold away (literal)
          gy[i] += ky * vm;
        }
      }
      s16x4 sid, sgx, sgy;
      #pragma unroll
      for (int i = 0; i < 4; ++i) { sid[i] = bfr(idv[i]); sgx[i] = bfr(gx[i]); sgy[i] = bfr(gy[i]); }
      *reinterpret_cast<s16x4*>(&Ys[apix * YS +          cq * 4]) = sid;
      *reinterpret_cast<s16x4*>(&Ys[apix * YS + NC     + cq * 4]) = sgx;
      *reinterpret_cast<s16x4*>(&Ys[apix * YS + 2 * NC + cq * 4]) = sgy;
      *reinterpret_cast<float4*>(&XC[apix * XCS + cq * 4]) =
          make_float4(idv[0], idv[1], idv[2], idv[3]);
    }
    __syncthreads();   // Ys/XC ready

    // ---------- issue NEXT tile's loads (fly under both GEMMs) ----------
    if (t + 1 < NTILES)
      issue_loads(xin, b, h, wbase0 + (t + 1) * 32 + apix, cq, pf, vld);

    // ---------- GEMM1: H^T = W0 * Y^T + b0 (A in registers) ----------
    bf16x8 yb[2][3];
    #pragma unroll
    for (int p2 = 0; p2 < 2; ++p2)
      #pragma unroll
      for (int kk = 0; kk < 3; ++kk)
        yb[p2][kk] = *reinterpret_cast<const bf16x8*>(&Ys[(p2 * 16 + l15) * YS + kk * 32 + g * 8]);

    f32x4 acc[4][2];
    #pragma unroll
    for (int hti = 0; hti < 4; ++hti) { acc[hti][0] = bb[hti]; acc[hti][1] = bb[hti]; }
    #pragma unroll
    for (int hti = 0; hti < 4; ++hti)
      #pragma unroll
      for (int kk = 0; kk < 3; ++kk) {
        acc[hti][0] = __builtin_amdgcn_mfma_f32_16x16x32_bf16(af1[hti][kk], yb[0][kk], acc[hti][0], 0, 0, 0);
        acc[hti][1] = __builtin_amdgcn_mfma_f32_16x16x32_bf16(af1[hti][kk], yb[1][kk], acc[hti][1], 0, 0, 0);
      }
    #pragma unroll
    for (int hti = 0; hti < 4; ++hti) {
      const int ht = wid * 4 + hti;
      #pragma unroll
      for (int p2 = 0; p2 < 2; ++p2) {
        s16x4 hv;
        #pragma unroll
        for (int r = 0; r < 4; ++r) hv[r] = bfr(acc[hti][p2][r]);
        *reinterpret_cast<s16x4*>(&Hs[(p2 * 16 + l15) * HS + ht * 16 + 4 * g]) = hv;
      }
    }
    __syncthreads();   // Hs ready

    // ---------- GEMM2: D^T = W1 * H^T + epilogue ----------
    f32x4 dacc = {0.f, 0.f, 0.f, 0.f};
    #pragma unroll
    for (int kk = 0; kk < 8; ++kk) {
      const bf16x8 hf = *reinterpret_cast<const bf16x8*>(&Hs[(pt * 16 + l15) * HS + kk * 32 + g * 8]);
      dacc = __builtin_amdgcn_mfma_f32_16x16x32_bf16(af2[kk], hf, dacc, 0, 0, 0);
    }

    const int pix = pt * 16 + l15;
    const u32 p = (u32)(rowpix + wbase + pix);
    u32 r0 = 0u, r1 = p;
    tf2x32(fk0, fk1, r0, r1);
    const u32 bits = r0 ^ r1;              // partitionable threefry (verified R4)
    const float uu = __uint_as_float((bits >> 9) | 0x3F800000u) - 1.0f;
    const float m  = (uu > 0.5f) ? 1.f : 0.f;

    const float4 xcv = *reinterpret_cast<const float4*>(&XC[pix * XCS + ct * 16 + 4 * g]);
    const float xc4[4] = {xcv.x, xcv.y, xcv.z, xcv.w};
    float ov[4];
    #pragma unroll
    for (int r = 0; r < 4; ++r) {
      const int c = ct * 16 + 4 * g + r;
      const float tt = xc4[r] + dacc[r] * m;
      const float s = 1.f / (1.f + __expf(-tt));
      ov[r] = (c < 3) ? xc4[r] : s;
    }
    *reinterpret_cast<float4*>(xout + (rowpix + wbase + pix) * NC + ct * 16 + 4 * g) =
        make_float4(ov[0], ov[1], ov[2], ov[3]);

    __syncthreads();   // WAR: Ys/XC/Hs readers done before next tile overwrites
  }
}

// ---------------- host ----------------
static void fold_key(u32 step, u32& fk0, u32& fk1) {
  u32 x0 = 0u, x1 = step;
  tf2x32(0u, 42u, x0, x1);
  fk0 = x0; fk1 = x1;
}

extern "C" void kernel_launch(void* const* d_in, const int* in_sizes, int n_in,
                              void* d_out, int out_size, void* d_ws, size_t ws_size,
                              hipStream_t stream) {
  const float* x  = (const float*)d_in[0];
  const float* w0 = (const float*)d_in[1];
  const float* b0 = (const float*)d_in[2];
  const float* w1 = (const float*)d_in[3];
  float* xmid = (float*)d_ws;     // 67 MB step-1 intermediate
  float* xout = (float*)d_out;

  u32 fka0, fka1, fkb0, fkb1;
  fold_key(0u, fka0, fka1);
  fold_key(1u, fkb0, fkb1);

  dim3 grid(NB * NH * (NW / 128)), blk(256);
  nca_step_mfma<<<grid, blk, 0, stream>>>(x,    xmid, w0, b0, w1, fka0, fka1);
  nca_step_mfma<<<grid, blk, 0, stream>>>(xmid, xout, w0, b0, w1, fkb0, fkb1);
}